// Round 4
// baseline (431.829 us; speedup 1.0000x reference)
//
#include <hip/hip_runtime.h>

// Shapes (fixed): B=4, L=4096, DIM=1024, INNER=512, DSTATE=8, DTRANK=64, KSZ=3
// BL = 16384 rows. Chunked scan: 128 chunks x 32 steps, chunk-major summaries.

using bf16x8 = __attribute__((ext_vector_type(8))) short;
using f32x4  = __attribute__((ext_vector_type(4))) float;

__device__ __forceinline__ unsigned short f2bf(float f) {
  unsigned int u = __float_as_uint(f);
  u = u + 0x7fffu + ((u >> 16) & 1u);   // round-to-nearest-even
  return (unsigned short)(u >> 16);
}
__device__ __forceinline__ float bf2f(unsigned short u) {
  return __uint_as_float(((unsigned int)u) << 16);
}

// fast softplus: log1p(exp(x)) via hardware exp/log; exact passthrough for x>15
__device__ __forceinline__ float fsoftplus(float x) {
  return (x > 15.f) ? x : __logf(1.f + __expf(x));
}

__device__ __forceinline__ float ftanh(float x) {
  float v = fminf(fmaxf(x, -15.f), 15.f);
  float e = __expf(2.f * v);
  return (e - 1.f) / (e + 1.f);
}

// ---------------- fp32 -> bf16 conversion (4 elems/thread) ----------------
__global__ __launch_bounds__(256) void cvt_bf16_kernel(
    const float* __restrict__ in, unsigned short* __restrict__ out, int n4) {
  int i = blockIdx.x * 256 + threadIdx.x;
  if (i < n4) {
    float4 v = ((const float4*)in)[i];
    ushort4 o;
    o.x = f2bf(v.x); o.y = f2bf(v.y); o.z = f2bf(v.z); o.w = f2bf(v.w);
    ((ushort4*)out)[i] = o;
  }
}

// pad/convert W_xproj (80x512 f32) -> (128x512 bf16, rows 80..127 = 0)
__global__ __launch_bounds__(256) void cvt_wxp_kernel(
    const float* __restrict__ Wx, unsigned short* __restrict__ out) {
  int i = blockIdx.x * 256 + threadIdx.x;  // 128*512
  int row = i >> 9;
  out[i] = (row < 80) ? f2bf(Wx[i]) : (unsigned short)0;
}

// ---------------- bf16 GEMM: C[m,n] = sum_k A[m,k]*B[n,k] ----------------
// A: MxK row-major bf16, B: NxK row-major bf16 (B^T layout).
// 128x128 tile, BK=32, 4 waves, 4x4 mfma_f32_16x16x32_bf16.
// LDS layout is chunk-major [kblk][row] (16B chunks): fragment ds_read_b128
// banks = (row*4)%32 -> 2-way aliasing only (free), vs 8-way in row-major.
// Staging: wave wv owns kblk=wv, two row-halves; linear 1KB DMA bursts.
template <bool BF16OUT>
__global__ __launch_bounds__(256) void gemm_bt(
    const unsigned short* __restrict__ A,
    const unsigned short* __restrict__ B,
    void* __restrict__ Cp, int M, int N, int K) {
  __shared__ short As[4096];   // [kblk][row][8]
  __shared__ short Bs[4096];
  const int m0 = blockIdx.x * 128;
  const int n0 = blockIdx.y * 128;
  const int lane = threadIdx.x & 63;
  const int wv = threadIdx.x >> 6;
  const int wm = (wv >> 1) * 64;
  const int wn = (wv & 1) * 64;
  f32x4 acc[4][4] = {};
  // staging: this wave stages kblk=wv, rows {lane, 64+lane}
  const unsigned short* gA0 = A + (size_t)(m0 + lane) * K + wv * 8;
  const unsigned short* gA1 = A + (size_t)(m0 + 64 + lane) * K + wv * 8;
  const unsigned short* gB0 = B + (size_t)(n0 + lane) * K + wv * 8;
  const unsigned short* gB1 = B + (size_t)(n0 + 64 + lane) * K + wv * 8;
  short* lA0 = &As[wv * 1024];          // wave-uniform LDS bases
  short* lA1 = &As[wv * 1024 + 512];
  short* lB0 = &Bs[wv * 1024];
  short* lB1 = &Bs[wv * 1024 + 512];
  const int r = lane & 15;
  const int q = lane >> 4;
  for (int k0 = 0; k0 < K; k0 += 32) {
    __syncthreads();
    __builtin_amdgcn_global_load_lds((const __attribute__((address_space(1))) void*)(const void*)gA0,
                                     (__attribute__((address_space(3))) void*)(void*)lA0, 16, 0, 0);
    __builtin_amdgcn_global_load_lds((const __attribute__((address_space(1))) void*)(const void*)gA1,
                                     (__attribute__((address_space(3))) void*)(void*)lA1, 16, 0, 0);
    __builtin_amdgcn_global_load_lds((const __attribute__((address_space(1))) void*)(const void*)gB0,
                                     (__attribute__((address_space(3))) void*)(void*)lB0, 16, 0, 0);
    __builtin_amdgcn_global_load_lds((const __attribute__((address_space(1))) void*)(const void*)gB1,
                                     (__attribute__((address_space(3))) void*)(void*)lB1, 16, 0, 0);
    gA0 += 32; gA1 += 32; gB0 += 32; gB1 += 32;
    __syncthreads();
    bf16x8 av[4], bv[4];
#pragma unroll
    for (int i = 0; i < 4; ++i)
      av[i] = *(const bf16x8*)&As[q * 1024 + (wm + i * 16 + r) * 8];
#pragma unroll
    for (int j = 0; j < 4; ++j)
      bv[j] = *(const bf16x8*)&Bs[q * 1024 + (wn + j * 16 + r) * 8];
#pragma unroll
    for (int i = 0; i < 4; ++i)
#pragma unroll
      for (int j = 0; j < 4; ++j)
        acc[i][j] = __builtin_amdgcn_mfma_f32_16x16x32_bf16(av[i], bv[j], acc[i][j], 0, 0, 0);
  }
  // C/D layout: col = lane&15, row = (lane>>4)*4 + reg
#pragma unroll
  for (int i = 0; i < 4; ++i)
#pragma unroll
    for (int j = 0; j < 4; ++j)
#pragma unroll
      for (int t = 0; t < 4; ++t) {
        size_t off = (size_t)(m0 + wm + i * 16 + q * 4 + t) * N + (n0 + wn + j * 16 + r);
        if (BF16OUT) ((unsigned short*)Cp)[off] = f2bf(acc[i][j][t]);
        else         ((float*)Cp)[off] = acc[i][j][t];
      }
}

// ---------------- depthwise conv (k=3, pad=1) + SiLU ----------------
// h is bf16 now. xb half -> bf16 xbbf; zb half -> bf16 cat[..., 512:1024]
__global__ __launch_bounds__(256) void conv_silu_kernel(
    const unsigned short* __restrict__ h, const float* __restrict__ Kx,
    const float* __restrict__ Kz,
    unsigned short* __restrict__ xbbf, unsigned short* __restrict__ cat) {
  int tid = blockIdx.x * 256 + threadIdx.x;  // over 16384*1024
  int ch = tid & 1023;
  int bl = tid >> 10;
  int l = bl & 4095;
  float k0, k1, k2;
  int c;
  if (ch < 512) { c = ch;       k0 = Kx[c * 3]; k1 = Kx[c * 3 + 1]; k2 = Kx[c * 3 + 2]; }
  else          { c = ch - 512; k0 = Kz[c * 3]; k1 = Kz[c * 3 + 1]; k2 = Kz[c * 3 + 2]; }
  size_t idx = (size_t)bl * 1024 + ch;
  float um = (l > 0)    ? bf2f(h[idx - 1024]) : 0.f;
  float u0 = bf2f(h[idx]);
  float up = (l < 4095) ? bf2f(h[idx + 1024]) : 0.f;
  float v = um * k0 + u0 * k1 + up * k2;
  float o = v / (1.f + __expf(-v));  // silu
  if (ch < 512) xbbf[(size_t)bl * 512 + c] = f2bf(o);
  else          cat[idx] = f2bf(o);
}

// ---------------- split proj: dtr -> bf16, b/c -> tanh ----------------
__global__ __launch_bounds__(256) void prep_dtbc_kernel(
    const float* __restrict__ proj, unsigned short* __restrict__ dtr,
    float* __restrict__ bterm, float* __restrict__ cterm) {
  int i = blockIdx.x * 256 + threadIdx.x;  // 16384*128
  int row = i >> 7, col = i & 127;
  float v = proj[i];
  if (col < 64)      dtr[row * 64 + col] = f2bf(v);
  else if (col < 72) bterm[row * 8 + (col - 64)] = ftanh(v);
  else if (col < 80) cterm[row * 8 + (col - 72)] = ftanh(v);
}

// ---------------- chunked selective scan (128 chunks x 32 steps) ----------
// One thread owns one (b, c, chunk) with all 8 DSTATE lanes in registers.
// draw/xb are bf16 streams; summaries chunk-major [chunk][bcs] (coalesced).
// delta = clip(softplus(draw + b_dt[c]), 1e-4, 1) computed inline.
__global__ __launch_bounds__(256) void scan_p1(
    const unsigned short* __restrict__ draw, const float* __restrict__ bterm,
    const unsigned short* __restrict__ xb, const float* __restrict__ A_log,
    const float* __restrict__ bdt,
    float* __restrict__ Aprod, float* __restrict__ Bpart) {
  int tid = threadIdx.x;
  int gid = blockIdx.x;
  int chunk = gid & 127, half = (gid >> 7) & 1, b = gid >> 8;
  int c = half * 256 + tid;
  float4 a0 = *(const float4*)&A_log[c * 8];
  float4 a1 = *(const float4*)&A_log[c * 8 + 4];
  float na[8] = {a0.x, a0.y, a0.z, a0.w, a1.x, a1.y, a1.z, a1.w};
#pragma unroll
  for (int s = 0; s < 8; ++s) na[s] = -(fsoftplus(na[s]) + 1e-4f);
  float bb = bdt[c];
  int l0 = chunk * 32;
  size_t base  = ((size_t)b * 4096 + l0) * 512 + c;
  size_t bbase = ((size_t)b * 4096 + l0) * 8;
  float S[8] = {}, Ap[8] = {1.f, 1.f, 1.f, 1.f, 1.f, 1.f, 1.f, 1.f};
  for (int i = 0; i < 32; ++i) {
    float dr = bf2f(draw[base]) + bb;
    float xv = bf2f(xb[base]);
    float delta = fminf(fmaxf(fsoftplus(dr), 1e-4f), 1.f);
    float4 bt0 = *(const float4*)&bterm[bbase];
    float4 bt1 = *(const float4*)&bterm[bbase + 4];
    float bt[8] = {bt0.x, bt0.y, bt0.z, bt0.w, bt1.x, bt1.y, bt1.z, bt1.w};
#pragma unroll
    for (int s = 0; s < 8; ++s) {
      float dec = fminf(fmaxf(__expf(delta * na[s]), 1e-4f), 1.f);
      float btx = bt[s] * xv;
      S[s] = dec * S[s] + (btx - dec * btx);
      Ap[s] *= dec;
    }
    base += 512; bbase += 8;
  }
  size_t o = (size_t)chunk * 16384 + ((size_t)(b * 512 + c)) * 8;
  *(float4*)&Aprod[o]     = make_float4(Ap[0], Ap[1], Ap[2], Ap[3]);
  *(float4*)&Aprod[o + 4] = make_float4(Ap[4], Ap[5], Ap[6], Ap[7]);
  *(float4*)&Bpart[o]     = make_float4(S[0], S[1], S[2], S[3]);
  *(float4*)&Bpart[o + 4] = make_float4(S[4], S[5], S[6], S[7]);
}

__global__ __launch_bounds__(256) void scan_p2(
    const float* __restrict__ Aprod, const float* __restrict__ Bpart,
    float* __restrict__ initst) {
  int t = blockIdx.x * 256 + threadIdx.x;  // 16384 threads: one (b,c,s)
  float st = 0.f;
  for (int ch = 0; ch < 128; ++ch) {
    size_t o = (size_t)ch * 16384 + t;
    initst[o] = st;
    st = Aprod[o] * st + Bpart[o];  // coalesced across threads
  }
}

__global__ __launch_bounds__(256) void scan_p3(
    const unsigned short* __restrict__ draw, const float* __restrict__ bterm,
    const float* __restrict__ cterm, const unsigned short* __restrict__ xb,
    const float* __restrict__ A_log, const float* __restrict__ bdt,
    const float* __restrict__ Dp,
    const float* __restrict__ initst, unsigned short* __restrict__ cat) {
  int tid = threadIdx.x;
  int gid = blockIdx.x;
  int chunk = gid & 127, half = (gid >> 7) & 1, b = gid >> 8;
  int c = half * 256 + tid;
  float4 a0 = *(const float4*)&A_log[c * 8];
  float4 a1 = *(const float4*)&A_log[c * 8 + 4];
  float na[8] = {a0.x, a0.y, a0.z, a0.w, a1.x, a1.y, a1.z, a1.w};
#pragma unroll
  for (int s = 0; s < 8; ++s) na[s] = -(fsoftplus(na[s]) + 1e-4f);
  float bb = bdt[c];
  float Dv = Dp[c];
  size_t o = (size_t)chunk * 16384 + ((size_t)(b * 512 + c)) * 8;
  float4 s0 = *(const float4*)&initst[o];
  float4 s1 = *(const float4*)&initst[o + 4];
  float S[8] = {s0.x, s0.y, s0.z, s0.w, s1.x, s1.y, s1.z, s1.w};
  int l0 = chunk * 32;
  size_t base  = ((size_t)b * 4096 + l0) * 512 + c;
  size_t bbase = ((size_t)b * 4096 + l0) * 8;
  size_t cbase = ((size_t)b * 4096 + l0) * 1024 + c;   // y -> cat[..., :512]
  for (int i = 0; i < 32; ++i) {
    float dr = bf2f(draw[base]) + bb;
    float xv = bf2f(xb[base]);
    float delta = fminf(fmaxf(fsoftplus(dr), 1e-4f), 1.f);
    float4 bt0 = *(const float4*)&bterm[bbase];
    float4 bt1 = *(const float4*)&bterm[bbase + 4];
    float4 ct0 = *(const float4*)&cterm[bbase];
    float4 ct1 = *(const float4*)&cterm[bbase + 4];
    float bt[8] = {bt0.x, bt0.y, bt0.z, bt0.w, bt1.x, bt1.y, bt1.z, bt1.w};
    float ct[8] = {ct0.x, ct0.y, ct0.z, ct0.w, ct1.x, ct1.y, ct1.z, ct1.w};
    float acc = Dv * xv;
#pragma unroll
    for (int s = 0; s < 8; ++s) {
      float dec = fminf(fmaxf(__expf(delta * na[s]), 1e-4f), 1.f);
      float btx = bt[s] * xv;
      S[s] = dec * S[s] + (btx - dec * btx);
      acc += S[s] * ct[s];
    }
    cat[cbase] = f2bf(acc);
    base += 512; bbase += 8; cbase += 1024;
  }
}

// ---------------- launch ----------------
extern "C" void kernel_launch(void* const* d_in, const int* in_sizes, int n_in,
                              void* d_out, int out_size, void* d_ws, size_t ws_size,
                              hipStream_t stream) {
  (void)in_sizes; (void)n_in; (void)out_size; (void)ws_size;
  const float* x       = (const float*)d_in[0];
  const float* W_in    = (const float*)d_in[1];
  const float* Kx      = (const float*)d_in[2];
  const float* Kz      = (const float*)d_in[3];
  const float* W_xproj = (const float*)d_in[4];
  const float* W_dt    = (const float*)d_in[5];
  const float* b_dt    = (const float*)d_in[6];
  const float* A_log   = (const float*)d_in[7];
  const float* Dp      = (const float*)d_in[8];
  const float* W_out   = (const float*)d_in[9];
  float* out = (float*)d_out;

  // workspace layout (~108 MB), no risky overlays
  char* w = (char*)d_ws;
  unsigned short* xbf    = (unsigned short*)(w);              // 33.5MB x bf16; reused as cat
  unsigned short* draw16 = (unsigned short*)(w + 33554432);   // 16.8MB delta_raw bf16
  float* bterm  = (float*)(w + 50331648);                     // 0.5MB
  float* cterm  = (float*)(w + 50855936);                     // 0.5MB
  float* Aprod  = (float*)(w + 51380224);                     // 8MB [chunk][bcs]
  float* Bpart  = (float*)(w + 59768832);                     // 8MB
  float* initst = (float*)(w + 68157440);                     // 8MB
  unsigned short* winbf  = (unsigned short*)(w + 76546048);   // 2MB
  unsigned short* woutbf = (unsigned short*)(w + 78643200);   // 2MB
  unsigned short* dtr    = (unsigned short*)(w + 80740352);   // 2MB (16384x64 bf16)
  unsigned short* wxp_bf = (unsigned short*)(w + 82837504);   // 128KB
  unsigned short* wd_bf  = (unsigned short*)(w + 82968576);   // 64KB
  unsigned short* xbbf   = (unsigned short*)(w + 83034112);   // 16.8MB bf16 xb
  float* proj            = (float*)(w + 99811328);            // 8.4MB (16384x128 f32)
  unsigned short* h = (unsigned short*)out;  // d_out head holds bf16 h scratch

  cvt_bf16_kernel<<<16384, 256, 0, stream>>>(x, xbf, 4194304);
  cvt_bf16_kernel<<<1024, 256, 0, stream>>>(W_in, winbf, 262144);
  cvt_bf16_kernel<<<1024, 256, 0, stream>>>(W_out, woutbf, 262144);
  cvt_bf16_kernel<<<32, 256, 0, stream>>>(W_dt, wd_bf, 8192);
  cvt_wxp_kernel<<<256, 256, 0, stream>>>(W_xproj, wxp_bf);

  gemm_bt<true><<<dim3(128, 8), 256, 0, stream>>>(xbf, winbf, h, 16384, 1024, 1024);

  conv_silu_kernel<<<65536, 256, 0, stream>>>(h, Kx, Kz, xbbf, xbf /*cat*/);

  gemm_bt<false><<<dim3(128, 1), 256, 0, stream>>>(xbbf, wxp_bf, proj, 16384, 128, 512);
  prep_dtbc_kernel<<<8192, 256, 0, stream>>>(proj, dtr, bterm, cterm);
  gemm_bt<true><<<dim3(128, 4), 256, 0, stream>>>(dtr, wd_bf, draw16, 16384, 512, 64);

  scan_p1<<<1024, 256, 0, stream>>>(draw16, bterm, xbbf, A_log, b_dt, Aprod, Bpart);
  scan_p2<<<64, 256, 0, stream>>>(Aprod, Bpart, initst);
  scan_p3<<<1024, 256, 0, stream>>>(draw16, bterm, cterm, xbbf, A_log, b_dt, Dp, initst, xbf /*cat*/);

  gemm_bt<false><<<dim3(128, 8), 256, 0, stream>>>(xbf, woutbf, out, 16384, 1024, 1024);
}

// Round 5
// 377.889 us; speedup vs baseline: 1.1427x; 1.1427x over previous
//
#include <hip/hip_runtime.h>

// Shapes (fixed): B=4, L=4096, DIM=1024, INNER=512, DSTATE=8, DTRANK=64, KSZ=3
// BL = 16384 rows. Chunked scan: 128 chunks x 32 steps, chunk-major summaries.

using bf16x8 = __attribute__((ext_vector_type(8))) short;
using f32x4  = __attribute__((ext_vector_type(4))) float;

__device__ __forceinline__ unsigned short f2bf(float f) {
  unsigned int u = __float_as_uint(f);
  u = u + 0x7fffu + ((u >> 16) & 1u);   // round-to-nearest-even
  return (unsigned short)(u >> 16);
}
__device__ __forceinline__ float bf2f(unsigned short u) {
  return __uint_as_float(((unsigned int)u) << 16);
}

// fast softplus: log1p(exp(x)) via hardware exp/log; exact passthrough for x>15
__device__ __forceinline__ float fsoftplus(float x) {
  return (x > 15.f) ? x : __logf(1.f + __expf(x));
}

__device__ __forceinline__ float ftanh(float x) {
  float v = fminf(fmaxf(x, -15.f), 15.f);
  float e = __expf(2.f * v);
  return (e - 1.f) / (e + 1.f);
}

// ---------------- fp32 -> bf16 conversion (4 elems/thread) ----------------
__global__ __launch_bounds__(256) void cvt_bf16_kernel(
    const float* __restrict__ in, unsigned short* __restrict__ out, int n4) {
  int i = blockIdx.x * 256 + threadIdx.x;
  if (i < n4) {
    float4 v = ((const float4*)in)[i];
    ushort4 o;
    o.x = f2bf(v.x); o.y = f2bf(v.y); o.z = f2bf(v.z); o.w = f2bf(v.w);
    ((ushort4*)out)[i] = o;
  }
}

// pad/convert W_xproj (80x512 f32) -> (128x512 bf16, rows 80..127 = 0)
__global__ __launch_bounds__(256) void cvt_wxp_kernel(
    const float* __restrict__ Wx, unsigned short* __restrict__ out) {
  int i = blockIdx.x * 256 + threadIdx.x;  // 128*512
  int row = i >> 9;
  out[i] = (row < 80) ? f2bf(Wx[i]) : (unsigned short)0;
}

// ---------------- bf16 GEMM: C[m,n] = sum_k A[m,k]*B[n,k] ----------------
// A: MxK row-major bf16, B: NxK row-major bf16 (B^T layout).
// 128x128 tile, BK=32, 4 waves, 4x4 mfma_f32_16x16x32_bf16.
// Staging = round-3 pattern (lane>>2 = row within 16-row group, 64B segments,
// proven-fast) BUT with the 16B chunk index XOR-swizzled within each row's
// 64B line: kc = (lane&3) ^ ((lane>>3)&3). Same global transactions; the
// fragment ds_read_b128 banks become (16*(r&1) + 4*(q^((r>>1)&3))) -> all 8
// bank-groups covered 2-way (free) instead of 8-deep on 2 groups.
template <bool BF16OUT>
__global__ __launch_bounds__(256) void gemm_bt(
    const unsigned short* __restrict__ A,
    const unsigned short* __restrict__ B,
    void* __restrict__ Cp, int M, int N, int K) {
  __shared__ short As[128 * 32];
  __shared__ short Bs[128 * 32];
  const int m0 = blockIdx.x * 128;
  const int n0 = blockIdx.y * 128;
  const int lane = threadIdx.x & 63;
  const int wv = threadIdx.x >> 6;
  const int wm = (wv >> 1) * 64;
  const int wn = (wv & 1) * 64;
  f32x4 acc[4][4] = {};
  // swizzled staging offset: row-local = lane>>2, chunk = (lane&3)^((lane>>3)&3)
  const int off = (lane >> 2) * K + (((lane & 3) ^ ((lane >> 3) & 3)) << 3);
  const unsigned short* gA0 = A + (size_t)(m0 + wv * 32) * K + off;
  const unsigned short* gA1 = gA0 + 16 * (size_t)K;
  const unsigned short* gB0 = B + (size_t)(n0 + wv * 32) * K + off;
  const unsigned short* gB1 = gB0 + 16 * (size_t)K;
  short* lA0 = &As[wv * 1024];          // wave-uniform LDS bases
  short* lA1 = &As[wv * 1024 + 512];
  short* lB0 = &Bs[wv * 1024];
  short* lB1 = &Bs[wv * 1024 + 512];
  const int r = lane & 15;
  const int q = lane >> 4;
  const int xq = (q ^ ((r >> 1) & 3)) * 8;   // swizzled chunk for fragment reads
  for (int k0 = 0; k0 < K; k0 += 32) {
    __syncthreads();
    __builtin_amdgcn_global_load_lds((const __attribute__((address_space(1))) void*)(const void*)gA0,
                                     (__attribute__((address_space(3))) void*)(void*)lA0, 16, 0, 0);
    __builtin_amdgcn_global_load_lds((const __attribute__((address_space(1))) void*)(const void*)gA1,
                                     (__attribute__((address_space(3))) void*)(void*)lA1, 16, 0, 0);
    __builtin_amdgcn_global_load_lds((const __attribute__((address_space(1))) void*)(const void*)gB0,
                                     (__attribute__((address_space(3))) void*)(void*)lB0, 16, 0, 0);
    __builtin_amdgcn_global_load_lds((const __attribute__((address_space(1))) void*)(const void*)gB1,
                                     (__attribute__((address_space(3))) void*)(void*)lB1, 16, 0, 0);
    gA0 += 32; gA1 += 32; gB0 += 32; gB1 += 32;
    __syncthreads();
    bf16x8 av[4], bv[4];
#pragma unroll
    for (int i = 0; i < 4; ++i)
      av[i] = *(const bf16x8*)&As[(wm + i * 16 + r) * 32 + xq];
#pragma unroll
    for (int j = 0; j < 4; ++j)
      bv[j] = *(const bf16x8*)&Bs[(wn + j * 16 + r) * 32 + xq];
#pragma unroll
    for (int i = 0; i < 4; ++i)
#pragma unroll
      for (int j = 0; j < 4; ++j)
        acc[i][j] = __builtin_amdgcn_mfma_f32_16x16x32_bf16(av[i], bv[j], acc[i][j], 0, 0, 0);
  }
  // C/D layout: col = lane&15, row = (lane>>4)*4 + reg
#pragma unroll
  for (int i = 0; i < 4; ++i)
#pragma unroll
    for (int j = 0; j < 4; ++j)
#pragma unroll
      for (int t = 0; t < 4; ++t) {
        size_t off2 = (size_t)(m0 + wm + i * 16 + q * 4 + t) * N + (n0 + wn + j * 16 + r);
        if (BF16OUT) ((unsigned short*)Cp)[off2] = f2bf(acc[i][j][t]);
        else         ((float*)Cp)[off2] = acc[i][j][t];
      }
}

// ---------------- depthwise conv (k=3, pad=1) + SiLU ----------------
// h is bf16. xb half -> bf16 xbbf; zb half -> bf16 cat[..., 512:1024]
__global__ __launch_bounds__(256) void conv_silu_kernel(
    const unsigned short* __restrict__ h, const float* __restrict__ Kx,
    const float* __restrict__ Kz,
    unsigned short* __restrict__ xbbf, unsigned short* __restrict__ cat) {
  int tid = blockIdx.x * 256 + threadIdx.x;  // over 16384*1024
  int ch = tid & 1023;
  int bl = tid >> 10;
  int l = bl & 4095;
  float k0, k1, k2;
  int c;
  if (ch < 512) { c = ch;       k0 = Kx[c * 3]; k1 = Kx[c * 3 + 1]; k2 = Kx[c * 3 + 2]; }
  else          { c = ch - 512; k0 = Kz[c * 3]; k1 = Kz[c * 3 + 1]; k2 = Kz[c * 3 + 2]; }
  size_t idx = (size_t)bl * 1024 + ch;
  float um = (l > 0)    ? bf2f(h[idx - 1024]) : 0.f;
  float u0 = bf2f(h[idx]);
  float up = (l < 4095) ? bf2f(h[idx + 1024]) : 0.f;
  float v = um * k0 + u0 * k1 + up * k2;
  float o = v / (1.f + __expf(-v));  // silu
  if (ch < 512) xbbf[(size_t)bl * 512 + c] = f2bf(o);
  else          cat[idx] = f2bf(o);
}

// ---------------- split proj: dtr -> bf16, b/c -> tanh ----------------
__global__ __launch_bounds__(256) void prep_dtbc_kernel(
    const float* __restrict__ proj, unsigned short* __restrict__ dtr,
    float* __restrict__ bterm, float* __restrict__ cterm) {
  int i = blockIdx.x * 256 + threadIdx.x;  // 16384*128
  int row = i >> 7, col = i & 127;
  float v = proj[i];
  if (col < 64)      dtr[row * 64 + col] = f2bf(v);
  else if (col < 72) bterm[row * 8 + (col - 64)] = ftanh(v);
  else if (col < 80) cterm[row * 8 + (col - 72)] = ftanh(v);
}

// ---------------- chunked selective scan (128 chunks x 32 steps) ----------
// One thread owns one (b, c, chunk) with all 8 DSTATE lanes in registers.
// draw/xb are bf16 streams; summaries chunk-major [chunk][bcs] (coalesced).
// delta = clip(softplus(draw + b_dt[c]), 1e-4, 1) computed inline.
__global__ __launch_bounds__(256) void scan_p1(
    const unsigned short* __restrict__ draw, const float* __restrict__ bterm,
    const unsigned short* __restrict__ xb, const float* __restrict__ A_log,
    const float* __restrict__ bdt,
    float* __restrict__ Aprod, float* __restrict__ Bpart) {
  int tid = threadIdx.x;
  int gid = blockIdx.x;
  int chunk = gid & 127, half = (gid >> 7) & 1, b = gid >> 8;
  int c = half * 256 + tid;
  float4 a0 = *(const float4*)&A_log[c * 8];
  float4 a1 = *(const float4*)&A_log[c * 8 + 4];
  float na[8] = {a0.x, a0.y, a0.z, a0.w, a1.x, a1.y, a1.z, a1.w};
#pragma unroll
  for (int s = 0; s < 8; ++s) na[s] = -(fsoftplus(na[s]) + 1e-4f);
  float bb = bdt[c];
  int l0 = chunk * 32;
  size_t base  = ((size_t)b * 4096 + l0) * 512 + c;
  size_t bbase = ((size_t)b * 4096 + l0) * 8;
  float S[8] = {}, Ap[8] = {1.f, 1.f, 1.f, 1.f, 1.f, 1.f, 1.f, 1.f};
  for (int i = 0; i < 32; ++i) {
    float dr = bf2f(draw[base]) + bb;
    float xv = bf2f(xb[base]);
    float delta = fminf(fmaxf(fsoftplus(dr), 1e-4f), 1.f);
    float4 bt0 = *(const float4*)&bterm[bbase];
    float4 bt1 = *(const float4*)&bterm[bbase + 4];
    float bt[8] = {bt0.x, bt0.y, bt0.z, bt0.w, bt1.x, bt1.y, bt1.z, bt1.w};
#pragma unroll
    for (int s = 0; s < 8; ++s) {
      float dec = fminf(fmaxf(__expf(delta * na[s]), 1e-4f), 1.f);
      float btx = bt[s] * xv;
      S[s] = dec * S[s] + (btx - dec * btx);
      Ap[s] *= dec;
    }
    base += 512; bbase += 8;
  }
  size_t o = (size_t)chunk * 16384 + ((size_t)(b * 512 + c)) * 8;
  *(float4*)&Aprod[o]     = make_float4(Ap[0], Ap[1], Ap[2], Ap[3]);
  *(float4*)&Aprod[o + 4] = make_float4(Ap[4], Ap[5], Ap[6], Ap[7]);
  *(float4*)&Bpart[o]     = make_float4(S[0], S[1], S[2], S[3]);
  *(float4*)&Bpart[o + 4] = make_float4(S[4], S[5], S[6], S[7]);
}

__global__ __launch_bounds__(256) void scan_p2(
    const float* __restrict__ Aprod, const float* __restrict__ Bpart,
    float* __restrict__ initst) {
  int t = blockIdx.x * 256 + threadIdx.x;  // 16384 threads: one (b,c,s)
  float st = 0.f;
  for (int ch = 0; ch < 128; ++ch) {
    size_t o = (size_t)ch * 16384 + t;
    initst[o] = st;
    st = Aprod[o] * st + Bpart[o];  // coalesced across threads
  }
}

__global__ __launch_bounds__(256) void scan_p3(
    const unsigned short* __restrict__ draw, const float* __restrict__ bterm,
    const float* __restrict__ cterm, const unsigned short* __restrict__ xb,
    const float* __restrict__ A_log, const float* __restrict__ bdt,
    const float* __restrict__ Dp,
    const float* __restrict__ initst, unsigned short* __restrict__ cat) {
  int tid = threadIdx.x;
  int gid = blockIdx.x;
  int chunk = gid & 127, half = (gid >> 7) & 1, b = gid >> 8;
  int c = half * 256 + tid;
  float4 a0 = *(const float4*)&A_log[c * 8];
  float4 a1 = *(const float4*)&A_log[c * 8 + 4];
  float na[8] = {a0.x, a0.y, a0.z, a0.w, a1.x, a1.y, a1.z, a1.w};
#pragma unroll
  for (int s = 0; s < 8; ++s) na[s] = -(fsoftplus(na[s]) + 1e-4f);
  float bb = bdt[c];
  float Dv = Dp[c];
  size_t o = (size_t)chunk * 16384 + ((size_t)(b * 512 + c)) * 8;
  float4 s0 = *(const float4*)&initst[o];
  float4 s1 = *(const float4*)&initst[o + 4];
  float S[8] = {s0.x, s0.y, s0.z, s0.w, s1.x, s1.y, s1.z, s1.w};
  int l0 = chunk * 32;
  size_t base  = ((size_t)b * 4096 + l0) * 512 + c;
  size_t bbase = ((size_t)b * 4096 + l0) * 8;
  size_t cbase = ((size_t)b * 4096 + l0) * 1024 + c;   // y -> cat[..., :512]
  for (int i = 0; i < 32; ++i) {
    float dr = bf2f(draw[base]) + bb;
    float xv = bf2f(xb[base]);
    float delta = fminf(fmaxf(fsoftplus(dr), 1e-4f), 1.f);
    float4 bt0 = *(const float4*)&bterm[bbase];
    float4 bt1 = *(const float4*)&bterm[bbase + 4];
    float4 ct0 = *(const float4*)&cterm[bbase];
    float4 ct1 = *(const float4*)&cterm[bbase + 4];
    float bt[8] = {bt0.x, bt0.y, bt0.z, bt0.w, bt1.x, bt1.y, bt1.z, bt1.w};
    float ct[8] = {ct0.x, ct0.y, ct0.z, ct0.w, ct1.x, ct1.y, ct1.z, ct1.w};
    float acc = Dv * xv;
#pragma unroll
    for (int s = 0; s < 8; ++s) {
      float dec = fminf(fmaxf(__expf(delta * na[s]), 1e-4f), 1.f);
      float btx = bt[s] * xv;
      S[s] = dec * S[s] + (btx - dec * btx);
      acc += S[s] * ct[s];
    }
    cat[cbase] = f2bf(acc);
    base += 512; bbase += 8; cbase += 1024;
  }
}

// ---------------- launch ----------------
extern "C" void kernel_launch(void* const* d_in, const int* in_sizes, int n_in,
                              void* d_out, int out_size, void* d_ws, size_t ws_size,
                              hipStream_t stream) {
  (void)in_sizes; (void)n_in; (void)out_size; (void)ws_size;
  const float* x       = (const float*)d_in[0];
  const float* W_in    = (const float*)d_in[1];
  const float* Kx      = (const float*)d_in[2];
  const float* Kz      = (const float*)d_in[3];
  const float* W_xproj = (const float*)d_in[4];
  const float* W_dt    = (const float*)d_in[5];
  const float* b_dt    = (const float*)d_in[6];
  const float* A_log   = (const float*)d_in[7];
  const float* Dp      = (const float*)d_in[8];
  const float* W_out   = (const float*)d_in[9];
  float* out = (float*)d_out;

  // workspace layout (~108 MB), no risky overlays
  char* w = (char*)d_ws;
  unsigned short* xbf    = (unsigned short*)(w);              // 33.5MB x bf16; reused as cat
  unsigned short* draw16 = (unsigned short*)(w + 33554432);   // 16.8MB delta_raw bf16
  float* bterm  = (float*)(w + 50331648);                     // 0.5MB
  float* cterm  = (float*)(w + 50855936);                     // 0.5MB
  float* Aprod  = (float*)(w + 51380224);                     // 8MB [chunk][bcs]
  float* Bpart  = (float*)(w + 59768832);                     // 8MB
  float* initst = (float*)(w + 68157440);                     // 8MB
  unsigned short* winbf  = (unsigned short*)(w + 76546048);   // 2MB
  unsigned short* woutbf = (unsigned short*)(w + 78643200);   // 2MB
  unsigned short* dtr    = (unsigned short*)(w + 80740352);   // 2MB (16384x64 bf16)
  unsigned short* wxp_bf = (unsigned short*)(w + 82837504);   // 128KB
  unsigned short* wd_bf  = (unsigned short*)(w + 82968576);   // 64KB
  unsigned short* xbbf   = (unsigned short*)(w + 83034112);   // 16.8MB bf16 xb
  float* proj            = (float*)(w + 99811328);            // 8.4MB (16384x128 f32)
  unsigned short* h = (unsigned short*)out;  // d_out head holds bf16 h scratch

  cvt_bf16_kernel<<<16384, 256, 0, stream>>>(x, xbf, 4194304);
  cvt_bf16_kernel<<<1024, 256, 0, stream>>>(W_in, winbf, 262144);
  cvt_bf16_kernel<<<1024, 256, 0, stream>>>(W_out, woutbf, 262144);
  cvt_bf16_kernel<<<32, 256, 0, stream>>>(W_dt, wd_bf, 8192);
  cvt_wxp_kernel<<<256, 256, 0, stream>>>(W_xproj, wxp_bf);

  gemm_bt<true><<<dim3(128, 8), 256, 0, stream>>>(xbf, winbf, h, 16384, 1024, 1024);

  conv_silu_kernel<<<65536, 256, 0, stream>>>(h, Kx, Kz, xbbf, xbf /*cat*/);

  gemm_bt<false><<<dim3(128, 1), 256, 0, stream>>>(xbbf, wxp_bf, proj, 16384, 128, 512);
  prep_dtbc_kernel<<<8192, 256, 0, stream>>>(proj, dtr, bterm, cterm);
  gemm_bt<true><<<dim3(128, 4), 256, 0, stream>>>(dtr, wd_bf, draw16, 16384, 512, 64);

  scan_p1<<<1024, 256, 0, stream>>>(draw16, bterm, xbbf, A_log, b_dt, Aprod, Bpart);
  scan_p2<<<64, 256, 0, stream>>>(Aprod, Bpart, initst);
  scan_p3<<<1024, 256, 0, stream>>>(draw16, bterm, cterm, xbbf, A_log, b_dt, Dp, initst, xbf /*cat*/);

  gemm_bt<false><<<dim3(128, 8), 256, 0, stream>>>(xbf, woutbf, out, 16384, 1024, 1024);
}